// Round 16
// baseline (489.420 us; speedup 1.0000x reference)
//
#include <hip/hip_runtime.h>

// ---------------- problem constants ----------------
constexpr int cN     = 20000;
constexpr int cT     = 8;
constexpr int cFIN   = 64;
constexpr int cHEADS = 4;
constexpr int cF     = 32;
constexpr int cHID   = 128;        // cHEADS * cF
constexpr int cE     = 320000;
constexpr int cET    = cE + cN;    // edges + self loops
constexpr int cR     = cN * cT;    // 160000 batched rows, rho = t*N + n (t-major)
constexpr int cNW    = (cN + 63) / 64;   // 313 node windows of 64
constexpr float cLEAKY = 0.2f;

typedef __attribute__((ext_vector_type(8))) short bf16x8;   // MFMA A/B frag
typedef __attribute__((ext_vector_type(4))) float f32x4;    // MFMA C/D frag

static __device__ __forceinline__ unsigned short f2bfu(float f) {
    unsigned int u;
    __builtin_memcpy(&u, &f, 4);
    u += 0x7FFFu + ((u >> 16) & 1u);
    return (unsigned short)(u >> 16);
}
static __device__ __forceinline__ void unpack2(unsigned int v, float& lo, float& hi) {
    unsigned int ul = v << 16, uh = v & 0xFFFF0000u;
    __builtin_memcpy(&lo, &ul, 4);
    __builtin_memcpy(&hi, &uh, 4);
}
static __device__ __forceinline__ unsigned int pack2(float lo, float hi) {
    unsigned int ul, uh;
    __builtin_memcpy(&ul, &lo, 4);
    __builtin_memcpy(&uh, &hi, 4);
    ul += 0x7FFFu + ((ul >> 16) & 1u);
    uh += 0x7FFFu + ((uh >> 16) & 1u);
    return (ul >> 16) | (uh & 0xFFFF0000u);
}

// ---------------- weight conversion ----------------
__global__ void cvt_w_kernel(const float* W1, const float* W2, const float* lw1,
                             unsigned short* W1b, unsigned short* W2b, unsigned short* lw1b) {
    int i = blockIdx.x * 256 + threadIdx.x;
    if (i < cHID * cFIN)                      W1b[i] = f2bfu(W1[i]);
    else if (i < cHID * cFIN + cHID * cHID)   W2b[i - cHID * cFIN] = f2bfu(W2[i - cHID * cFIN]);
    else if (i < cHID * cFIN + cHID * cHID + cF * cHID)
        lw1b[i - cHID * cFIN - cHID * cHID] = f2bfu(lw1[i - cHID * cFIN - cHID * cHID]);
}

// ---------------- CSR build ----------------
__global__ void deg_init_kernel(int* deg) {
    int n = blockIdx.x * blockDim.x + threadIdx.x;
    if (n < cN) deg[n] = 1;   // self loop
}
__global__ void deg_count_kernel(const int* ei, int* deg) {
    int e = blockIdx.x * blockDim.x + threadIdx.x;
    if (e < cE) atomicAdd(&deg[ei[cE + e]], 1);
}
__global__ void scan_kernel(const int* deg, int* offs, int* cur) {
    __shared__ int lds[256];
    const int CH = 80;
    int tid  = threadIdx.x;
    int base = tid * CH;
    int tot = 0;
    for (int j = 0; j < CH; j++) {
        int idx = base + j;
        if (idx < cN) tot += deg[idx];
    }
    lds[tid] = tot;
    __syncthreads();
    for (int off = 1; off < 256; off <<= 1) {
        int v = (tid >= off) ? lds[tid - off] : 0;
        __syncthreads();
        lds[tid] += v;
        __syncthreads();
    }
    int run = lds[tid] - tot;
    for (int j = 0; j < CH; j++) {
        int idx = base + j;
        if (idx < cN) { offs[idx] = run; cur[idx] = run; run += deg[idx]; }
    }
    if (tid == 255) offs[cN] = lds[255];
}
__global__ void scatter_kernel(const int* ei, int* cur, int* csr) {
    int e = blockIdx.x * blockDim.x + threadIdx.x;
    if (e >= cET) return;
    int s, d;
    if (e < cE) { s = ei[e]; d = ei[cE + e]; }
    else        { s = e - cE; d = s; }
    int pos = atomicAdd(&cur[d], 1);
    csr[pos] = s;
}

// ---------------- window-local degree sort (64-node windows, 1 wave bitonic) ----------------
// perm[g*64+r] = node id of rank-r (by degree) node within window g; -1 for pad slots.
__global__ void perm_sort_kernel(const int* __restrict__ deg, int* __restrict__ perm) {
    int g    = blockIdx.x;
    int lane = threadIdx.x;          // 64 threads = 1 wave
    int node = g * 64 + lane;
    int key  = (node < cN) ? ((deg[node] << 6) | lane) : 0x7FFFFFFF;
    #pragma unroll
    for (int k = 2; k <= 64; k <<= 1) {
        #pragma unroll
        for (int j = k >> 1; j > 0; j >>= 1) {
            int other = __shfl_xor(key, j);
            bool dirUp = ((lane & k) == 0);
            bool lower = ((lane & j) == 0);
            int mn = min(key, other), mx = max(key, other);
            key = (lower == dirUp) ? mn : mx;
        }
    }
    perm[g * 64 + lane] = (key == 0x7FFFFFFF) ? -1 : (g * 64 + (key & 63));
}

// ---------------- GEMM1 (fused fp32->bf16 cvt of x) + scores ----------------
__global__ __launch_bounds__(256) void gemm1_fused_kernel(
        const float* __restrict__ x, const unsigned short* __restrict__ W,
        const float* __restrict__ a_src, const float* __restrict__ a_dst,
        unsigned short* __restrict__ hb, float* __restrict__ es, float* __restrict__ ed) {
    __shared__ float hl[64][132];
    int tid  = threadIdx.x;
    int wave = tid >> 6;
    int lane = tid & 63;
    int q    = lane >> 4;
    int mi   = lane & 15;
    int m0   = blockIdx.x * 64 + wave * 16;

    int rho = m0 + mi;
    int t = rho / cN;
    int n = rho - t * cN;
    const float* xr = x + (size_t)n * (cT * cFIN) + t * cFIN;

    bf16x8 afrag[2];
    #pragma unroll
    for (int s = 0; s < 2; s++) {
        float4 v0 = *(const float4*)(xr + s * 32 + q * 8);
        float4 v1 = *(const float4*)(xr + s * 32 + q * 8 + 4);
        bf16x8 f;
        f[0] = (short)f2bfu(v0.x); f[1] = (short)f2bfu(v0.y);
        f[2] = (short)f2bfu(v0.z); f[3] = (short)f2bfu(v0.w);
        f[4] = (short)f2bfu(v1.x); f[5] = (short)f2bfu(v1.y);
        f[6] = (short)f2bfu(v1.z); f[7] = (short)f2bfu(v1.w);
        afrag[s] = f;
    }

    f32x4 acc[8];
    #pragma unroll
    for (int ct = 0; ct < 8; ct++) acc[ct] = (f32x4){0.f, 0.f, 0.f, 0.f};
    #pragma unroll
    for (int ct = 0; ct < 8; ct++) {
        int c = ct * 16 + mi;
        #pragma unroll
        for (int s = 0; s < 2; s++) {
            bf16x8 bfrag = *(const bf16x8*)(W + (size_t)c * cFIN + s * 32 + q * 8);
            acc[ct] = __builtin_amdgcn_mfma_f32_16x16x32_bf16(afrag[s], bfrag, acc[ct], 0, 0, 0);
        }
    }

    #pragma unroll
    for (int ct = 0; ct < 8; ct++)
        #pragma unroll
        for (int r = 0; r < 4; r++)
            hl[wave * 16 + q * 4 + r][ct * 16 + mi] = acc[ct][r];
    __syncthreads();

    {
        int r2 = tid & 63;
        int hd = tid >> 6;
        int rg = blockIdx.x * 64 + r2;
        const float* hr = &hl[r2][hd * cF];
        const float* sa = a_src + hd * cF;
        const float* da = a_dst + hd * cF;
        float s1 = 0.f, s2 = 0.f;
        #pragma unroll 8
        for (int f = 0; f < cF; f++) {
            float hv = hr[f];
            s1 += hv * sa[f];
            s2 += hv * da[f];
        }
        es[rg * cHEADS + hd] = s1;
        ed[rg * cHEADS + hd] = s2;
    }

    size_t base = (size_t)blockIdx.x * 64 * cHID;
    #pragma unroll
    for (int it = 0; it < 8; it++) {
        int g   = tid + it * 256;
        int row = g >> 5;
        int c4  = (g & 31) * 4;
        float4 v = *(const float4*)&hl[row][c4];
        unsigned int p0 = pack2(v.x, v.y), p1 = pack2(v.z, v.w);
        *(uint2*)(hb + base + (size_t)row * cHID + c4) = make_uint2(p0, p1);
    }
}

// ---------------- GEMM2 (bf16 A) + scores, K=128 ----------------
__global__ __launch_bounds__(256) void gemm2_mfma_kernel(
        const unsigned short* __restrict__ A, const unsigned short* __restrict__ W,
        const float* __restrict__ a_src, const float* __restrict__ a_dst,
        unsigned short* __restrict__ hb, float* __restrict__ es, float* __restrict__ ed) {
    __shared__ float hl[64][132];
    int tid  = threadIdx.x;
    int wave = tid >> 6;
    int lane = tid & 63;
    int q    = lane >> 4;
    int mi   = lane & 15;
    int m0   = blockIdx.x * 64 + wave * 16;

    bf16x8 afrag[4];
    #pragma unroll
    for (int s = 0; s < 4; s++)
        afrag[s] = *(const bf16x8*)(A + (size_t)(m0 + mi) * cHID + s * 32 + q * 8);

    f32x4 acc[8];
    #pragma unroll
    for (int ct = 0; ct < 8; ct++) acc[ct] = (f32x4){0.f, 0.f, 0.f, 0.f};
    #pragma unroll
    for (int ct = 0; ct < 8; ct++) {
        int c = ct * 16 + mi;
        #pragma unroll
        for (int s = 0; s < 4; s++) {
            bf16x8 bfrag = *(const bf16x8*)(W + (size_t)c * cHID + s * 32 + q * 8);
            acc[ct] = __builtin_amdgcn_mfma_f32_16x16x32_bf16(afrag[s], bfrag, acc[ct], 0, 0, 0);
        }
    }

    #pragma unroll
    for (int ct = 0; ct < 8; ct++)
        #pragma unroll
        for (int r = 0; r < 4; r++)
            hl[wave * 16 + q * 4 + r][ct * 16 + mi] = acc[ct][r];
    __syncthreads();

    {
        int r2 = tid & 63;
        int hd = tid >> 6;
        int rg = blockIdx.x * 64 + r2;
        const float* hr = &hl[r2][hd * cF];
        const float* sa = a_src + hd * cF;
        const float* da = a_dst + hd * cF;
        float s1 = 0.f, s2 = 0.f;
        #pragma unroll 8
        for (int f = 0; f < cF; f++) {
            float hv = hr[f];
            s1 += hv * sa[f];
            s2 += hv * da[f];
        }
        es[rg * cHEADS + hd] = s1;
        ed[rg * cHEADS + hd] = s2;
    }

    size_t base = (size_t)blockIdx.x * 64 * cHID;
    #pragma unroll
    for (int it = 0; it < 8; it++) {
        int g   = tid + it * 256;
        int row = g >> 5;
        int c4  = (g & 31) * 4;
        float4 v = *(const float4*)&hl[row][c4];
        unsigned int p0 = pack2(v.x, v.y), p1 = pack2(v.z, v.w);
        *(uint2*)(hb + base + (size_t)row * cHID + c4) = make_uint2(p0, p1);
    }
}

// ---------------- t-plane agg: 4 lanes/row (1 lane = 1 head, 32 features) ----------------
// grid = cNW*cT blocks (t = b&7, window g = b>>3); block = 64 rows of one plane,
// rows assigned via window-local degree-sorted perm -> waves get degree-similar rows.
__global__ __launch_bounds__(256) void agg_kernel(
        const unsigned short* __restrict__ hb, const float* __restrict__ es,
        const float* __restrict__ ed,
        const int* __restrict__ offs, const int* __restrict__ csr,
        const int* __restrict__ perm,
        const float* __restrict__ bias, unsigned short* __restrict__ outb) {
    int b    = blockIdx.x;
    int t    = b & 7;
    int g    = b >> 3;
    int lrow = threadIdx.x >> 2;        // 0..63
    int j    = threadIdx.x & 3;         // head, features 32j..32j+31
    int n    = perm[g * 64 + lrow];
    bool valid = (n >= 0);
    int s0 = 0, s1 = 0;
    if (valid) { s0 = offs[n]; s1 = offs[n + 1]; }
    int rho  = t * cN + (valid ? n : 0);
    float edn = valid ? ed[(size_t)rho * cHEADS + j] : 0.f;
    const char* hpc = (const char*)(hb + (size_t)t * cN * cHID);
    const char* epc = (const char*)(es + (size_t)t * cN * cHEADS);
    const char* cc  = (const char*)csr;
    unsigned jo = (unsigned)j * 64u;    // byte offset of this lane's 32 features
    unsigned ho = (unsigned)j * 4u;

    float4 a0 = {0,0,0,0}, a1 = {0,0,0,0}, a2 = {0,0,0,0}, a3 = {0,0,0,0};
    float4 a4 = {0,0,0,0}, a5 = {0,0,0,0}, a6 = {0,0,0,0}, a7 = {0,0,0,0};
    float den = 0.f;
    for (int i = s0; i < s1; i++) {
        int sa = *(const int*)(cc + (unsigned)i * 4u);
        const char* hrow = hpc + (((unsigned)sa) << 8) + jo;
        uint4 r0 = *(const uint4*)(hrow);
        uint4 r1 = *(const uint4*)(hrow + 16);
        uint4 r2 = *(const uint4*)(hrow + 32);
        uint4 r3 = *(const uint4*)(hrow + 48);
        float ea = *(const float*)(epc + (((unsigned)sa) << 4) + ho) + edn;
        ea = (ea >= 0.f) ? ea : cLEAKY * ea;
        float w = __expf(ea);
        den += w;
        float lo, hi;
        unpack2(r0.x, lo, hi); a0.x += w * lo; a0.y += w * hi;
        unpack2(r0.y, lo, hi); a0.z += w * lo; a0.w += w * hi;
        unpack2(r0.z, lo, hi); a1.x += w * lo; a1.y += w * hi;
        unpack2(r0.w, lo, hi); a1.z += w * lo; a1.w += w * hi;
        unpack2(r1.x, lo, hi); a2.x += w * lo; a2.y += w * hi;
        unpack2(r1.y, lo, hi); a2.z += w * lo; a2.w += w * hi;
        unpack2(r1.z, lo, hi); a3.x += w * lo; a3.y += w * hi;
        unpack2(r1.w, lo, hi); a3.z += w * lo; a3.w += w * hi;
        unpack2(r2.x, lo, hi); a4.x += w * lo; a4.y += w * hi;
        unpack2(r2.y, lo, hi); a4.z += w * lo; a4.w += w * hi;
        unpack2(r2.z, lo, hi); a5.x += w * lo; a5.y += w * hi;
        unpack2(r2.w, lo, hi); a5.z += w * lo; a5.w += w * hi;
        unpack2(r3.x, lo, hi); a6.x += w * lo; a6.y += w * hi;
        unpack2(r3.y, lo, hi); a6.z += w * lo; a6.w += w * hi;
        unpack2(r3.z, lo, hi); a7.x += w * lo; a7.y += w * hi;
        unpack2(r3.w, lo, hi); a7.z += w * lo; a7.w += w * hi;
    }
    if (valid) {
        float inv = 1.f / (den + 1e-16f);
        const float* bp = bias + j * 32;
        float4 b0 = *(const float4*)(bp + 0),  b1 = *(const float4*)(bp + 4);
        float4 b2 = *(const float4*)(bp + 8),  b3 = *(const float4*)(bp + 12);
        float4 b4 = *(const float4*)(bp + 16), b5 = *(const float4*)(bp + 20);
        float4 b6 = *(const float4*)(bp + 24), b7 = *(const float4*)(bp + 28);
        float v[32];
        v[0]=a0.x*inv+b0.x; v[1]=a0.y*inv+b0.y; v[2]=a0.z*inv+b0.z; v[3]=a0.w*inv+b0.w;
        v[4]=a1.x*inv+b1.x; v[5]=a1.y*inv+b1.y; v[6]=a1.z*inv+b1.z; v[7]=a1.w*inv+b1.w;
        v[8]=a2.x*inv+b2.x; v[9]=a2.y*inv+b2.y; v[10]=a2.z*inv+b2.z; v[11]=a2.w*inv+b2.w;
        v[12]=a3.x*inv+b3.x; v[13]=a3.y*inv+b3.y; v[14]=a3.z*inv+b3.z; v[15]=a3.w*inv+b3.w;
        v[16]=a4.x*inv+b4.x; v[17]=a4.y*inv+b4.y; v[18]=a4.z*inv+b4.z; v[19]=a4.w*inv+b4.w;
        v[20]=a5.x*inv+b5.x; v[21]=a5.y*inv+b5.y; v[22]=a5.z*inv+b5.z; v[23]=a5.w*inv+b5.w;
        v[24]=a6.x*inv+b6.x; v[25]=a6.y*inv+b6.y; v[26]=a6.z*inv+b6.z; v[27]=a6.w*inv+b6.w;
        v[28]=a7.x*inv+b7.x; v[29]=a7.y*inv+b7.y; v[30]=a7.z*inv+b7.z; v[31]=a7.w*inv+b7.w;
        #pragma unroll
        for (int k = 0; k < 32; k++) v[k] = (v[k] > 0.f) ? v[k] : expm1f(v[k]);
        unsigned short* orow = outb + (size_t)rho * cHID + j * 32;
        #pragma unroll
        for (int k = 0; k < 4; k++) {
            uint4 o;
            o.x = pack2(v[k*8+0], v[k*8+1]);
            o.y = pack2(v[k*8+2], v[k*8+3]);
            o.z = pack2(v[k*8+4], v[k*8+5]);
            o.w = pack2(v[k*8+6], v[k*8+7]);
            *(uint4*)(orow + k * 8) = o;
        }
    }
}

// ---------------- MFMA MLP head: relu(X@lw1.T+lb1)@lw2.T + lb2 -> out[rho] ----------------
__global__ __launch_bounds__(256) void TemporalGAT_20005957665499_kernel(
        const unsigned short* __restrict__ X, const unsigned short* __restrict__ lw1b,
        const float* __restrict__ lb1, const float* __restrict__ lw2,
        const float* __restrict__ lb2, float* __restrict__ out) {
    int tid  = threadIdx.x;
    int wave = tid >> 6;
    int lane = tid & 63;
    int q    = lane >> 4;
    int mi   = lane & 15;
    int m0   = blockIdx.x * 64 + wave * 16;

    bf16x8 afrag[4];
    #pragma unroll
    for (int s = 0; s < 4; s++)
        afrag[s] = *(const bf16x8*)(X + (size_t)(m0 + mi) * cHID + s * 32 + q * 8);

    f32x4 acc[2];
    acc[0] = (f32x4){0.f, 0.f, 0.f, 0.f};
    acc[1] = (f32x4){0.f, 0.f, 0.f, 0.f};
    #pragma unroll
    for (int ct = 0; ct < 2; ct++) {
        int c = ct * 16 + mi;
        #pragma unroll
        for (int s = 0; s < 4; s++) {
            bf16x8 bfrag = *(const bf16x8*)(lw1b + (size_t)c * cHID + s * 32 + q * 8);
            acc[ct] = __builtin_amdgcn_mfma_f32_16x16x32_bf16(afrag[s], bfrag, acc[ct], 0, 0, 0);
        }
    }

    float lb1a = lb1[mi], lb1b_ = lb1[16 + mi];
    float lw2a = lw2[mi], lw2b_ = lw2[16 + mi];
    float l2 = lb2[0];
    #pragma unroll
    for (int r = 0; r < 4; r++) {
        float va = acc[0][r] + lb1a; va = fmaxf(va, 0.f);
        float vb = acc[1][r] + lb1b_; vb = fmaxf(vb, 0.f);
        float v = va * lw2a + vb * lw2b_;
        v += __shfl_xor(v, 1);
        v += __shfl_xor(v, 2);
        v += __shfl_xor(v, 4);
        v += __shfl_xor(v, 8);
        if (mi == 0) out[m0 + q * 4 + r] = v + l2;   // rho-major == [T,N] output layout
    }
}

// ---------------- launch ----------------
extern "C" void kernel_launch(void* const* d_in, const int* in_sizes, int n_in,
                              void* d_out, int out_size, void* d_ws, size_t ws_size,
                              hipStream_t stream) {
    const float* x   = (const float*)d_in[0];   // [N,T,64] fp32
    const int*   ei  = (const int*)d_in[1];
    const float* W1  = (const float*)d_in[2];
    const float* as1 = (const float*)d_in[3];
    const float* ad1 = (const float*)d_in[4];
    const float* b1  = (const float*)d_in[5];
    const float* W2  = (const float*)d_in[6];
    const float* as2 = (const float*)d_in[7];
    const float* ad2 = (const float*)d_in[8];
    const float* b2  = (const float*)d_in[9];
    const float* lw1 = (const float*)d_in[10];
    const float* lb1 = (const float*)d_in[11];
    const float* lw2 = (const float*)d_in[12];
    const float* lb2 = (const float*)d_in[13];
    float* out = (float*)d_out;                 // [T,N,1] fp32 == rho-major
    (void)in_sizes; (void)n_in; (void)out_size; (void)ws_size;

    // workspace carve (~130 MB of 256 MB), 256B-aligned
    char* ws = (char*)d_ws;
    size_t o = 0;
    auto carveN = [&](size_t bytes) { void* p = ws + o; o += (bytes + 255) & ~(size_t)255; return p; };
    unsigned short* hb   = (unsigned short*)carveN((size_t)cR * cHID * 2);    // 41 MB
    unsigned short* xb2  = (unsigned short*)carveN((size_t)cR * cHID * 2);    // 41 MB
    unsigned short* xb3  = (unsigned short*)carveN((size_t)cR * cHID * 2);    // 41 MB
    unsigned short* W1b  = (unsigned short*)carveN((size_t)cHID * cFIN * 2);
    unsigned short* W2b  = (unsigned short*)carveN((size_t)cHID * cHID * 2);
    unsigned short* lw1b = (unsigned short*)carveN((size_t)cF * cHID * 2);
    float* es_buf  = (float*)carveN((size_t)cR * cHEADS * 4);                 // 2.6 MB
    float* ed_buf  = (float*)carveN((size_t)cR * cHEADS * 4);
    int*   deg     = (int*)carveN((size_t)cN * 4);
    int*   offs    = (int*)carveN((size_t)(cN + 1) * 4);
    int*   cursor  = (int*)carveN((size_t)cN * 4);
    int*   csr     = (int*)carveN((size_t)cET * 4);
    int*   perm    = (int*)carveN((size_t)cNW * 64 * 4);

    // ---- weight conversion ----
    cvt_w_kernel<<<(cHID * cFIN + cHID * cHID + cF * cHID + 255) / 256, 256, 0, stream>>>(
        W1, W2, lw1, W1b, W2b, lw1b);

    // ---- CSR build + window-local degree sort ----
    deg_init_kernel<<<(cN + 255) / 256, 256, 0, stream>>>(deg);
    deg_count_kernel<<<(cE + 255) / 256, 256, 0, stream>>>(ei, deg);
    scan_kernel<<<1, 256, 0, stream>>>(deg, offs, cursor);
    scatter_kernel<<<(cET + 255) / 256, 256, 0, stream>>>(ei, cursor, csr);
    perm_sort_kernel<<<cNW, 64, 0, stream>>>(deg, perm);

    // ---- layer 1 (x read + cvt fused into GEMM) ----
    gemm1_fused_kernel<<<cR / 64, 256, 0, stream>>>(x, W1b, as1, ad1, hb, es_buf, ed_buf);
    agg_kernel<<<cNW * cT, 256, 0, stream>>>(hb, es_buf, ed_buf, offs, csr, perm, b1, xb2);
    // ---- layer 2 ----
    gemm2_mfma_kernel<<<cR / 64, 256, 0, stream>>>(xb2, W2b, as2, ad2, hb, es_buf, ed_buf);
    agg_kernel<<<cNW * cT, 256, 0, stream>>>(hb, es_buf, ed_buf, offs, csr, perm, b2, xb3);
    // ---- MFMA MLP head -> out ----
    TemporalGAT_20005957665499_kernel<<<cR / 64, 256, 0, stream>>>(xb3, lw1b, lb1, lw2, lb2, out);
}